// Round 4
// baseline (2839.774 us; speedup 1.0000x reference)
//
#include <hip/hip_runtime.h>
#include <cstdint>
#include <cstddef>

typedef unsigned short u16;
typedef unsigned int u32;
typedef __attribute__((ext_vector_type(8))) short bh8;
typedef __attribute__((ext_vector_type(4))) float fx4;

#define T_TOK 2048
#define D_DIM 1024
#define H_DIM 512
#define N_EXP 64
#define K_TOP 6
#define N_ASG (T_TOK * K_TOP)   // 12288

__device__ __forceinline__ float bf2f(u16 v) {
    union { u32 u; float f; } c; c.u = ((u32)v) << 16; return c.f;
}
__device__ __forceinline__ u16 f2bf(float f) {
    union { u32 u; float f; } c; c.f = f;
    u32 u = c.u;
    return (u16)((u + 0x7fffu + ((u >> 16) & 1u)) >> 16);
}

// ---------------- RMSNorm (f32 in) -> xnb (bf16) ----------------
__global__ __launch_bounds__(256) void rmsnorm_k(
    const float* __restrict__ x, const float* __restrict__ nw, u16* __restrict__ xnb)
{
    int t = blockIdx.x, tid = threadIdx.x;
    int d0 = tid << 2;
    float4 xv = *(const float4*)(x + (size_t)t * D_DIM + d0);
    float ss = xv.x * xv.x + xv.y * xv.y + xv.z * xv.z + xv.w * xv.w;
    #pragma unroll
    for (int o = 32; o > 0; o >>= 1) ss += __shfl_down(ss, o);
    __shared__ float red[4];
    if ((tid & 63) == 0) red[tid >> 6] = ss;
    __syncthreads();
    float ms = (red[0] + red[1] + red[2] + red[3]) * (1.f / (float)D_DIM);
    float sc = rsqrtf(ms + 1.1920929e-07f);
    float4 wv = *(const float4*)(nw + d0);
    ushort4 ob;
    ob.x = f2bf(xv.x * sc * wv.x);
    ob.y = f2bf(xv.y * sc * wv.y);
    ob.z = f2bf(xv.z * sc * wv.z);
    ob.w = f2bf(xv.w * sc * wv.w);
    *(ushort4*)(xnb + (size_t)t * D_DIM + d0) = ob;
}

// ---------------- router with fused fp32 norm: raw[t][e] (all fp32) ----------------
__global__ __launch_bounds__(256) void routernorm_k(
    const float* __restrict__ x, const float* __restrict__ nw,
    const float* __restrict__ Wr, float* __restrict__ raw)
{
    int t = blockIdx.x, tid = threadIdx.x;
    __shared__ float xs[D_DIM];
    __shared__ float ps[256];
    __shared__ float red[4];
    int d0 = tid << 2;
    float4 xv = *(const float4*)(x + (size_t)t * D_DIM + d0);
    float ss = xv.x * xv.x + xv.y * xv.y + xv.z * xv.z + xv.w * xv.w;
    #pragma unroll
    for (int o = 32; o > 0; o >>= 1) ss += __shfl_down(ss, o);
    if ((tid & 63) == 0) red[tid >> 6] = ss;
    __syncthreads();
    float ms = (red[0] + red[1] + red[2] + red[3]) * (1.f / (float)D_DIM);
    float sc = rsqrtf(ms + 1.1920929e-07f);
    float4 wv = *(const float4*)(nw + d0);
    float4 xf;
    xf.x = xv.x * sc * wv.x;
    xf.y = xv.y * sc * wv.y;
    xf.z = xv.z * sc * wv.z;
    xf.w = xv.w * sc * wv.w;
    *(float4*)&xs[d0] = xf;
    __syncthreads();
    int e = tid & 63, part = tid >> 6;
    const float* wr = Wr + (size_t)e * D_DIM + part * 256;
    const float* xp = &xs[part * 256];
    float s = 0.f;
    #pragma unroll 8
    for (int i = 0; i < 256; i += 4) {
        float4 w4 = *(const float4*)(wr + i);
        s += xp[i] * w4.x + xp[i + 1] * w4.y + xp[i + 2] * w4.z + xp[i + 3] * w4.w;
    }
    ps[tid] = s;
    __syncthreads();
    if (part == 0) raw[(size_t)t * N_EXP + e] = ps[e] + ps[64 + e] + ps[128 + e] + ps[192 + e];
}

// ---------------- top-k (one wave per token), fp32 ----------------
__global__ void topk_k(const float* __restrict__ raw, const float* __restrict__ ebias,
                       int* __restrict__ cnt, int* __restrict__ tki, float* __restrict__ tkw)
{
    int t = blockIdx.x, lane = threadIdx.x;
    float r = raw[(size_t)t * N_EXP + lane];
    float cur = r + ebias[lane];
    int selI[K_TOP]; float selR[K_TOP];
    #pragma unroll
    for (int k = 0; k < K_TOP; ++k) {
        float v = cur; int id = lane;
        #pragma unroll
        for (int o = 32; o > 0; o >>= 1) {
            float v2 = __shfl_down(v, o); int i2 = __shfl_down(id, o);
            if (v2 > v || (v2 == v && i2 < id)) { v = v2; id = i2; }
        }
        id = __shfl(id, 0);
        if (lane == id) cur = -3.4e38f;
        selI[k] = id;
        selR[k] = __shfl(r, id);
    }
    float s = 0.f;
    #pragma unroll
    for (int k = 0; k < K_TOP; ++k) s += selR[k];
    if (lane < K_TOP) {
        tki[t * K_TOP + lane] = selI[lane];
        tkw[t * K_TOP + lane] = selR[lane] / s;
        atomicAdd(&cnt[selI[lane]], 1);
    }
}

__global__ void scan_k(const int* __restrict__ cnt, int* __restrict__ offs, int* __restrict__ fill)
{
    if (threadIdx.x == 0) {
        int s = 0;
        for (int e = 0; e < N_EXP; ++e) { offs[e] = s; fill[e] = s; s += cnt[e]; }
        offs[N_EXP] = s;
    }
}

__global__ void fill_k(const int* __restrict__ tki, const float* __restrict__ tkw,
                       int* __restrict__ fill, int* __restrict__ atok, float* __restrict__ aw)
{
    int t = blockIdx.x, lane = threadIdx.x;
    if (lane < K_TOP) {
        int e = tki[t * K_TOP + lane];
        int p = atomicAdd(&fill[e], 1);
        atok[p] = t;
        aw[p] = tkw[t * K_TOP + lane];
    }
}

// ============ fused per-expert FFN: h=xn@W1+b1; hg=h*silu(h@Wg); acc+=w*(hg@W2+b2) ============
// 32-row slab per block, 256 threads = 4 waves. h/hg live entirely in LDS (bf16).
// Weights are FP32 [k][n]; gathered per-lane-column, converted to bf16, staged transposed
// into Bs[64 cols][32 k] (u16 stride 36).
template<int ROUTED>
__global__ __launch_bounds__(256) void moe_ffn_k(
    const u16* __restrict__ xnb,
    const float* __restrict__ W1b, const float* __restrict__ Wg,
    const float* __restrict__ W2b,
    const float* __restrict__ b1b, const float* __restrict__ b2b,
    const int* __restrict__ offs, const int* __restrict__ atok,
    const float* __restrict__ aw, float* __restrict__ accG)
{
    int e = blockIdx.z;
    int start = ROUTED ? offs[e] : 0;
    int end   = ROUTED ? offs[e + 1] : T_TOK;
    int rowBase = start + (blockIdx.y << 5);
    if (rowBase >= end) return;
    int rows = end - rowBase; if (rows > 32) rows = 32;

    __shared__ int   tok[32];
    __shared__ float wt[32];
    __shared__ u16 hA[32 * 520];
    __shared__ u16 hG[32 * 520];
    __shared__ u16 As[32 * 32];
    __shared__ u16 Bs[64 * 36];

    int tid = threadIdx.x;
    if (tid < 32) {
        int cl = rowBase + tid; if (cl >= end) cl = end - 1;
        tok[tid] = ROUTED ? atok[cl] : cl;
        wt[tid]  = ROUTED ? aw[cl] : 1.0f;
    }
    __syncthreads();

    const float* W1 = W1b + (size_t)e * (D_DIM * H_DIM);
    const float* W2 = W2b + (size_t)e * (D_DIM * H_DIM);
    const float* b1 = b1b + e * H_DIM;
    const float* b2 = b2b + e * D_DIM;

    int w = tid >> 6, lane = tid & 63, quad = lane >> 4, l15 = lane & 15;
    int sr2 = tid >> 3, sc2 = (tid & 7) << 2;

    // ---- phase 1: h = xn @ W1 + b1 (K=1024 -> N=512) ----
    for (int nc = 0; nc < 8; ++nc) {
        int n0 = nc << 6;
        fx4 a0 = {}; fx4 a1 = {};
        for (int kc = 0; kc < 32; ++kc) {
            int kb = kc << 5;
            int2 av = *(const int2*)(xnb + (size_t)tok[sr2] * D_DIM + kb + sc2);
            const float* cp = W1 + n0 + lane;
            int kx = kb + (w << 3);
            u32 p[4];
            #pragma unroll
            for (int jj = 0; jj < 4; ++jj) {
                u32 lo = f2bf(cp[(size_t)(kx + 2 * jj) * H_DIM]);
                u32 hi = f2bf(cp[(size_t)(kx + 2 * jj + 1) * H_DIM]);
                p[jj] = lo | (hi << 16);
            }
            __syncthreads();
            *(int2*)&As[sr2 * 32 + sc2] = av;
            u16* bsw = &Bs[lane * 36 + (w << 3)];
            uint2 q0; q0.x = p[0]; q0.y = p[1];
            uint2 q1; q1.x = p[2]; q1.y = p[3];
            *(uint2*)bsw = q0;
            *(uint2*)(bsw + 4) = q1;
            __syncthreads();
            bh8 af0 = *(const bh8*)&As[l15 * 32 + (quad << 3)];
            bh8 af1 = *(const bh8*)&As[(16 + l15) * 32 + (quad << 3)];
            const u16* brp = &Bs[((w << 4) + l15) * 36 + (quad << 3)];
            union { bh8 v; uint2 u2[2]; } bf;
            bf.u2[0] = *(const uint2*)brp;
            bf.u2[1] = *(const uint2*)(brp + 4);
            a0 = __builtin_amdgcn_mfma_f32_16x16x32_bf16(af0, bf.v, a0, 0, 0, 0);
            a1 = __builtin_amdgcn_mfma_f32_16x16x32_bf16(af1, bf.v, a1, 0, 0, 0);
        }
        int col = n0 + (w << 4) + l15;
        float bv = b1[col];
        #pragma unroll
        for (int r = 0; r < 4; ++r) {
            hA[((quad << 2) + r) * 520 + col]      = f2bf(a0[r] + bv);
            hA[(16 + (quad << 2) + r) * 520 + col] = f2bf(a1[r] + bv);
        }
    }
    __syncthreads();

    // ---- phase 2: hg = h * silu(h @ Wg) (K=512 -> N=512) ----
    for (int nc = 0; nc < 8; ++nc) {
        int n0 = nc << 6;
        fx4 a0 = {}; fx4 a1 = {};
        for (int kc = 0; kc < 16; ++kc) {
            int kb = kc << 5;
            const float* cp = Wg + n0 + lane;
            int kx = kb + (w << 3);
            u32 p[4];
            #pragma unroll
            for (int jj = 0; jj < 4; ++jj) {
                u32 lo = f2bf(cp[(size_t)(kx + 2 * jj) * H_DIM]);
                u32 hi = f2bf(cp[(size_t)(kx + 2 * jj + 1) * H_DIM]);
                p[jj] = lo | (hi << 16);
            }
            __syncthreads();
            u16* bsw = &Bs[lane * 36 + (w << 3)];
            uint2 q0; q0.x = p[0]; q0.y = p[1];
            uint2 q1; q1.x = p[2]; q1.y = p[3];
            *(uint2*)bsw = q0;
            *(uint2*)(bsw + 4) = q1;
            __syncthreads();
            bh8 af0 = *(const bh8*)&hA[l15 * 520 + kb + (quad << 3)];
            bh8 af1 = *(const bh8*)&hA[(16 + l15) * 520 + kb + (quad << 3)];
            const u16* brp = &Bs[((w << 4) + l15) * 36 + (quad << 3)];
            union { bh8 v; uint2 u2[2]; } bf;
            bf.u2[0] = *(const uint2*)brp;
            bf.u2[1] = *(const uint2*)(brp + 4);
            a0 = __builtin_amdgcn_mfma_f32_16x16x32_bf16(af0, bf.v, a0, 0, 0, 0);
            a1 = __builtin_amdgcn_mfma_f32_16x16x32_bf16(af1, bf.v, a1, 0, 0, 0);
        }
        int col = n0 + (w << 4) + l15;
        #pragma unroll
        for (int r = 0; r < 4; ++r) {
            int r0 = (quad << 2) + r;
            float h0 = bf2f(hA[r0 * 520 + col]);
            float g0 = a0[r];
            hG[r0 * 520 + col] = f2bf(h0 * g0 * (1.f / (1.f + __expf(-g0))));
            int r1 = 16 + r0;
            float h1 = bf2f(hA[r1 * 520 + col]);
            float g1 = a1[r];
            hG[r1 * 520 + col] = f2bf(h1 * g1 * (1.f / (1.f + __expf(-g1))));
        }
    }
    __syncthreads();

    // ---- phase 3: acc[tok] += wt * (hg @ W2 + b2) (K=512 -> N=1024) ----
    for (int nc = 0; nc < 16; ++nc) {
        int n0 = nc << 6;
        fx4 a0 = {}; fx4 a1 = {};
        for (int kc = 0; kc < 16; ++kc) {
            int kb = kc << 5;
            const float* cp = W2 + n0 + lane;
            int kx = kb + (w << 3);
            u32 p[4];
            #pragma unroll
            for (int jj = 0; jj < 4; ++jj) {
                u32 lo = f2bf(cp[(size_t)(kx + 2 * jj) * D_DIM]);
                u32 hi = f2bf(cp[(size_t)(kx + 2 * jj + 1) * D_DIM]);
                p[jj] = lo | (hi << 16);
            }
            __syncthreads();
            u16* bsw = &Bs[lane * 36 + (w << 3)];
            uint2 q0; q0.x = p[0]; q0.y = p[1];
            uint2 q1; q1.x = p[2]; q1.y = p[3];
            *(uint2*)bsw = q0;
            *(uint2*)(bsw + 4) = q1;
            __syncthreads();
            bh8 af0 = *(const bh8*)&hG[l15 * 520 + kb + (quad << 3)];
            bh8 af1 = *(const bh8*)&hG[(16 + l15) * 520 + kb + (quad << 3)];
            const u16* brp = &Bs[((w << 4) + l15) * 36 + (quad << 3)];
            union { bh8 v; uint2 u2[2]; } bf;
            bf.u2[0] = *(const uint2*)brp;
            bf.u2[1] = *(const uint2*)(brp + 4);
            a0 = __builtin_amdgcn_mfma_f32_16x16x32_bf16(af0, bf.v, a0, 0, 0, 0);
            a1 = __builtin_amdgcn_mfma_f32_16x16x32_bf16(af1, bf.v, a1, 0, 0, 0);
        }
        int col = n0 + (w << 4) + l15;
        float bv = b2[col];
        #pragma unroll
        for (int r = 0; r < 4; ++r) {
            int lr0 = (quad << 2) + r;
            if (lr0 < rows)
                atomicAdd(&accG[(size_t)tok[lr0] * D_DIM + col], wt[lr0] * (a0[r] + bv));
            int lr1 = 16 + lr0;
            if (lr1 < rows)
                atomicAdd(&accG[(size_t)tok[lr1] * D_DIM + col], wt[lr1] * (a1[r] + bv));
        }
    }
}

// ---------------- final: out = x + acc (all fp32) ----------------
__global__ __launch_bounds__(256) void final_k(
    const float* __restrict__ x, const float* __restrict__ acc, float* __restrict__ out)
{
    size_t i = ((size_t)blockIdx.x * 256 + threadIdx.x) << 2;
    float4 xv = *(const float4*)(x + i);
    float4 a = *(const float4*)(acc + i);
    float4 o;
    o.x = xv.x + a.x;
    o.y = xv.y + a.y;
    o.z = xv.z + a.z;
    o.w = xv.w + a.w;
    *(float4*)(out + i) = o;
}

extern "C" void kernel_launch(void* const* d_in, const int* in_sizes, int n_in,
                              void* d_out, int out_size, void* d_ws, size_t ws_size,
                              hipStream_t stream)
{
    const float* x     = (const float*)d_in[0];
    const float* nw    = (const float*)d_in[1];
    const float* Wr    = (const float*)d_in[2];
    const float* sW1   = (const float*)d_in[3];
    const float* sb1   = (const float*)d_in[4];
    const float* sW2   = (const float*)d_in[5];
    const float* sb2   = (const float*)d_in[6];
    const float* sWg   = (const float*)d_in[7];
    const float* rW1   = (const float*)d_in[8];
    const float* rb1   = (const float*)d_in[9];
    const float* rW2   = (const float*)d_in[10];
    const float* rb2   = (const float*)d_in[11];
    const float* rWg   = (const float*)d_in[12];
    const float* ebias = (const float*)d_in[13];
    float* out = (float*)d_out;
    (void)in_sizes; (void)n_in; (void)out_size; (void)ws_size;

    // total workspace ~12.8 MB
    char* wp = (char*)d_ws;
    auto alloc = [&](size_t b) { char* p = wp; wp += (b + 255) & ~(size_t)255; return p; };
    int*   cnt  = (int*)alloc(N_EXP * 4);
    int*   offs = (int*)alloc((N_EXP + 1) * 4);
    int*   fill = (int*)alloc(N_EXP * 4);
    int*   tki  = (int*)alloc((size_t)T_TOK * K_TOP * 4);
    float* tkw  = (float*)alloc((size_t)T_TOK * K_TOP * 4);
    int*   atok = (int*)alloc((size_t)N_ASG * 4);
    float* aw   = (float*)alloc((size_t)N_ASG * 4);
    float* raw  = (float*)alloc((size_t)T_TOK * N_EXP * 4);
    u16*   xnb  = (u16*)alloc((size_t)T_TOK * D_DIM * 2);
    float* acc  = (float*)alloc((size_t)T_TOK * D_DIM * 4);

    hipMemsetAsync(cnt, 0, N_EXP * 4, stream);
    hipMemsetAsync(acc, 0, (size_t)T_TOK * D_DIM * 4, stream);

    dim3 b256(256);
    rmsnorm_k<<<T_TOK, b256, 0, stream>>>(x, nw, xnb);
    routernorm_k<<<T_TOK, b256, 0, stream>>>(x, nw, Wr, raw);
    topk_k<<<T_TOK, dim3(64), 0, stream>>>(raw, ebias, cnt, tki, tkw);
    scan_k<<<1, dim3(64), 0, stream>>>(cnt, offs, fill);
    fill_k<<<T_TOK, dim3(64), 0, stream>>>(tki, tkw, fill, atok, aw);

    // routed experts (64) then shared experts (2 pseudo-experts, weight 1)
    moe_ffn_k<1><<<dim3(1, 64, N_EXP), b256, 0, stream>>>(
        xnb, rW1, rWg, rW2, rb1, rb2, offs, atok, aw, acc);
    moe_ffn_k<0><<<dim3(1, 64, 2), b256, 0, stream>>>(
        xnb, sW1, sWg, sW2, sb1, sb2, offs, atok, aw, acc);

    final_k<<<(T_TOK * D_DIM) / 1024, b256, 0, stream>>>(x, acc, out);
}